// Round 4
// baseline (162.273 us; speedup 1.0000x reference)
//
#include <hip/hip_runtime.h>
#include <stdint.h>

// B=1, R=128, L=256, IN=128, DM=32, DIM=128
// out[i,j,k] = x[i,j,k] + (1/R)*sum_{r,c,d} mp[r,j,c]*mp[r,i,d]*W2[k,c*32+d] + b2[k]
// mp[r,i,d]  = sum_e m[r,i,e]*W1[d,e] + b1[d]
//
// mpF[rt][kr][lane][j]  rt=(i*32+d)>>4 (512), kr=r>>5 (4):
//     value mp[r = kr*32 + (lane>>4)*8 + j][row = rt*16 + (lane&15)]
// W2f[nt][kc][lane][j]  nt=kout>>4 (8), kc=d-ish (32):
//     value W2t[kout=nt*16+(lane&15)][cd' = kc*32 + (lane>>4)*8 + j]
//
// LEDGER: r0=58us (Bs LDS, 9 barriers). r2=62 (B from L2: +4us). r1/r3:
// forced-occupancy / merged-d both SPILLED (WRITE_SIZE +50MB = scratch).
// Occupancy is pinned at 4 waves/SIMD by ~48 acc regs + ~60 VGPR in every
// healthy config -> optimize per-wave density, not waves.
//
// This round: j-split stepC. Gl (64 KiB) holds BOTH j-halves of one d-half.
// stepC waves 0-3 project j-half 0, waves 4-7 j-half 1; each wave owns TWO
// kout tiles, so each Gl ds_read_b128 feeds 2 MFMAs (was 1) and each Gl
// element is read by 4 waves (was 8): stepC LDS traffic 1MB -> 512KB/block.
// cacc stays 16 regs (j-half dim traded for kout dim) -> no new pressure.
// B operand from L2-resident mpF (r2-verified path). 5 barriers (was 9).

typedef __attribute__((ext_vector_type(8))) short bf16x8;
typedef __attribute__((ext_vector_type(4))) float f32x4;

#define MFMA16 __builtin_amdgcn_mfma_f32_16x16x32_bf16

__device__ __forceinline__ unsigned short f2bf(float f) {
    union { float f; unsigned int u; } x; x.f = f;
    unsigned int r = (x.u + 0x7fffu + ((x.u >> 16) & 1u)) >> 16;  // RNE
    return (unsigned short)r;
}

__device__ __forceinline__ bf16x8 load8f_bf(const float* p) {
    float4 v0 = *(const float4*)p;
    float4 v1 = *(const float4*)(p + 4);
    union { bf16x8 v; unsigned short u[8]; } r;
    r.u[0] = f2bf(v0.x); r.u[1] = f2bf(v0.y); r.u[2] = f2bf(v0.z); r.u[3] = f2bf(v0.w);
    r.u[4] = f2bf(v1.x); r.u[5] = f2bf(v1.y); r.u[6] = f2bf(v1.z); r.u[7] = f2bf(v1.w);
    return r.v;
}

// ---------------------------------------------------------------------------
// prep: blocks 0..511 -> mp GEMM -> mpF; blocks 512..575 -> W2 -> W2f
// ---------------------------------------------------------------------------
__global__ __launch_bounds__(256) void prep_kernel(
    const float* __restrict__ m, const float* __restrict__ W1,
    const float* __restrict__ pb1, const float* __restrict__ W2,
    unsigned short* __restrict__ mpF, unsigned short* __restrict__ W2f)
{
    const int bx = blockIdx.x;
    if (bx >= 512) {
        const int t    = (bx - 512) * 256 + threadIdx.x;   // 0..16383
        const int nt   = t >> 11;
        const int kc   = (t >> 6) & 31;
        const int lane = t & 63;
        const int ln   = lane & 15, q = lane >> 4;
        const float* src = W2 + (size_t)(nt * 16 + ln) * 1024 + kc;
        union { bf16x8 v; unsigned short u[8]; } r;
        #pragma unroll
        for (int j = 0; j < 8; ++j)
            r.u[j] = f2bf(src[(q * 8 + j) * 32]);
        *(bf16x8*)(W2f + (size_t)t * 8) = r.v;
        return;
    }
    const int lane = threadIdx.x & 63;
    const int w    = threadIdx.x >> 6;
    const int ln   = lane & 15, q = lane >> 4;
    const int tile = bx * 4 + w;          // 0..2047
    const int i    = tile >> 3;           // 0..255
    const int r0   = (tile & 7) * 16;     // r-tile base

    const float* Ap  = m  + ((size_t)(r0 + ln) * 256 + i) * 128 + q * 8;
    const float* Bp0 = W1 + (size_t)ln * 128 + q * 8;
    const float* Bp1 = W1 + (size_t)(16 + ln) * 128 + q * 8;

    f32x4 acc0 = {0.f, 0.f, 0.f, 0.f};
    f32x4 acc1 = {0.f, 0.f, 0.f, 0.f};
    #pragma unroll
    for (int ke = 0; ke < 4; ++ke) {
        bf16x8 a  = load8f_bf(Ap  + ke * 32);
        bf16x8 b0 = load8f_bf(Bp0 + ke * 32);
        bf16x8 b1 = load8f_bf(Bp1 + ke * 32);
        acc0 = MFMA16(a, b0, acc0, 0, 0, 0);
        acc1 = MFMA16(a, b1, acc1, 0, 0, 0);
    }
    const float bb0 = pb1[ln];
    const float bb1 = pb1[16 + ln];
    const int kr = r0 >> 5;
    const int qr = ((r0 >> 4) & 1) * 2 + (q >> 1);
    const int j0 = (q & 1) * 4;
    const size_t off0 = (size_t)(i * 2 + 0) * 2048 + kr * 512 + (qr * 16 + ln) * 8 + j0;
    const size_t off1 = (size_t)(i * 2 + 1) * 2048 + kr * 512 + (qr * 16 + ln) * 8 + j0;
    ushort4 o0, o1;
    o0.x = f2bf(acc0[0] + bb0); o0.y = f2bf(acc0[1] + bb0);
    o0.z = f2bf(acc0[2] + bb0); o0.w = f2bf(acc0[3] + bb0);
    o1.x = f2bf(acc1[0] + bb1); o1.y = f2bf(acc1[1] + bb1);
    o1.z = f2bf(acc1[2] + bb1); o1.w = f2bf(acc1[3] + bb1);
    *(ushort4*)(mpF + off0) = o0;
    *(ushort4*)(mpF + off1) = o1;
}

// ---------------------------------------------------------------------------
// fused helpers
// ---------------------------------------------------------------------------
// stepB: A and B both stream from global mpF (L2-resident, coalesced;
// verified r2). Ab: j-row base (this wave's wm row), c-halves at +0/+2048.
// Bb: i-slot base for this wave's wn group (+dhalf*2048 by caller); slot bn
// at +bn*4096.
__device__ __forceinline__ void stepB(const unsigned short* __restrict__ Ab,
                                      const unsigned short* __restrict__ Bb,
                                      f32x4 (&acc)[2][4])
{
    #pragma unroll
    for (int a = 0; a < 2; ++a)
        #pragma unroll
        for (int b = 0; b < 4; ++b)
            acc[a][b] = (f32x4){0.f, 0.f, 0.f, 0.f};
    #pragma unroll
    for (int ks = 0; ks < 4; ++ks) {
        bf16x8 av[2], bv[4];
        av[0] = *(const bf16x8*)(Ab + ks * 512);
        av[1] = *(const bf16x8*)(Ab + 2048 + ks * 512);
        #pragma unroll
        for (int bn = 0; bn < 4; ++bn)
            bv[bn] = *(const bf16x8*)(Bb + bn * 4096 + ks * 512);
        #pragma unroll
        for (int am = 0; am < 2; ++am)
            #pragma unroll
            for (int bn = 0; bn < 4; ++bn)
                acc[am][bn] = MFMA16(av[am], bv[bn], acc[am][bn], 0, 0, 0);
    }
}

// Write one j-half's G tiles into Gl at chunk base cbase (0 or 64).
// chunk = cbase + ln*4 + am*2 + (q>>1); sig = chunk>>3 (0..15). Pair p
// stored at slot p^sig; reader's (ln^sig) recovers pair ln, +16 pair ln+16.
__device__ __forceinline__ void gwriteC(unsigned short* __restrict__ Gl,
                                        const f32x4 (&acc)[2][4],
                                        int ln, int q, int wm, int wn, int cbase)
{
    #pragma unroll
    for (int am = 0; am < 2; ++am) {
        const int chunk = cbase + ln * 4 + am * 2 + (q >> 1);
        const int sig   = chunk >> 3;
        const int hbase = chunk * 256 + (q & 1) * 4;
        #pragma unroll
        for (int bn = 0; bn < 4; ++bn) {
            const int p  = (wn * 4 + bn) * 4 + wm;
            const int pp = p ^ sig;
            ushort4 g;
            g.x = f2bf(acc[am][bn][0]); g.y = f2bf(acc[am][bn][1]);
            g.z = f2bf(acc[am][bn][2]); g.w = f2bf(acc[am][bn][3]);
            *(ushort4*)(Gl + hbase + pp * 8) = g;
        }
    }
}

// j-split projection: this wave reads ONLY its j-half's chunks (cb = jh*64)
// and projects onto TWO kout tiles (wpA, wpB). Each ag read feeds 2 MFMAs.
__device__ __forceinline__ void stepC2(const unsigned short* __restrict__ Gl,
                                       const unsigned short* __restrict__ wpA,
                                       const unsigned short* __restrict__ wpB,
                                       int cb, int ln, int q,
                                       f32x4& c0, f32x4& c1, f32x4& c2, f32x4& c3)
{
    #pragma unroll
    for (int ks = 0; ks < 16; ++ks) {
        bf16x8 wa = *(const bf16x8*)(wpA + ks * 512);
        bf16x8 wb = *(const bf16x8*)(wpB + ks * 512);
        const int chunk = cb + ks * 4 + q;
        const int sig   = chunk >> 3;
        const unsigned short* gp = Gl + chunk * 256 + ((ln ^ sig) << 3);
        bf16x8 ag0 = *(const bf16x8*)gp;          // pairs 0..15
        bf16x8 ag1 = *(const bf16x8*)(gp + 128);  // pairs 16..31
        c0 = MFMA16(ag0, wa, c0, 0, 0, 0);
        c1 = MFMA16(ag1, wa, c1, 0, 0, 0);
        c2 = MFMA16(ag0, wb, c2, 0, 0, 0);
        c3 = MFMA16(ag1, wb, c3, 0, 0, 0);
    }
}

// ---------------------------------------------------------------------------
// fused: block = 8i x 8j (64 pairs). 2 d-phases; per phase Gl holds both
// j-halves (64 KiB). stepC j-split across waves, 2 kout tiles/wave.
// ---------------------------------------------------------------------------
__global__ __launch_bounds__(512, 4) void fused_kernel(
    const float* __restrict__ x, const float* __restrict__ b2,
    const unsigned short* __restrict__ mpF, const unsigned short* __restrict__ W2f,
    float* __restrict__ out)
{
    __shared__ __align__(16) unsigned char smem[65536];
    unsigned short* Gl = (unsigned short*)smem;            // 128 chunks x 256 shorts

    const int tid  = threadIdx.x;
    const int lane = tid & 63, w = tid >> 6;
    const int ln   = lane & 15, q = lane >> 4;
    const int wm   = w & 3, wn = w >> 2;

    const int i0 = blockIdx.x * 8;            // gridDim.x = 32
    const int j0 = blockIdx.y * 8;            // gridDim.y = 32

    const unsigned short* Ab0 = mpF + (size_t)((j0 + wm) * 2) * 2048 + lane * 8;
    const unsigned short* Ab1 = Ab0 + 16384;                   // +4 j rows
    const unsigned short* Bb  = mpF + (size_t)((i0 + wn * 4) * 2) * 2048 + lane * 8;

    // stepC role: j-half jh = w>>2; kout tiles kt0 = (w&3)*2, kt0+1.
    const int jh = w >> 2;
    const int cb = jh * 64;
    const unsigned short* wpA = W2f + (size_t)((w & 3) * 2) * 16384 + lane * 8;
    const unsigned short* wpB = wpA + 16384;

    f32x4 cacc[4];   // [0]=(kt0,pairs0-15) [1]=(kt0,16-31) [2]=(kt1,0-15) [3]=(kt1,16-31)
    #pragma unroll
    for (int t = 0; t < 4; ++t) cacc[t] = (f32x4){0.f, 0.f, 0.f, 0.f};
    f32x4 acc[2][4];

    // ---- d-phase 0 ----
    stepB(Ab0, Bb, acc);
    gwriteC(Gl, acc, ln, q, wm, wn, 0);     // j-half 0 -> chunks 0..63
    stepB(Ab1, Bb, acc);
    gwriteC(Gl, acc, ln, q, wm, wn, 64);    // j-half 1 -> chunks 64..127
    __syncthreads();                         // Gl(d0) ready
    stepC2(Gl, wpA, wpB, cb, ln, q, cacc[0], cacc[1], cacc[2], cacc[3]);
    __syncthreads();                         // Gl(d0) reads done

    // ---- d-phase 1 ----
    stepB(Ab0, Bb + 2048, acc);
    gwriteC(Gl, acc, ln, q, wm, wn, 0);
    stepB(Ab1, Bb + 2048, acc);
    gwriteC(Gl, acc, ln, q, wm, wn, 64);
    __syncthreads();                         // Gl(d1) ready

    // prefetch x while stepC2 runs
    float4 xv[4];
    size_t gb[4];
    #pragma unroll
    for (int e = 0; e < 4; ++e) {
        const int fid = e * 512 + tid;                 // 0..2047 float4 units
        const int po  = fid >> 5, kq = fid & 31;
        gb[e] = ((size_t)(i0 + (po >> 3)) * 256 + (j0 + (po & 7))) * 128 + kq * 4;
        xv[e] = *(const float4*)(x + gb[e]);
    }

    stepC2(Gl, wpA + 8192, wpB + 8192, cb, ln, q, cacc[0], cacc[1], cacc[2], cacc[3]);
    __syncthreads();                         // all Gl reads done -> Ep

    // ---- epilogue: LDS transpose (XOR-swizzled cols), coalesced out ----
    // wave w holds (jh, kt0/kt1) x 32 pairs: pair = pt*16 + q*4 + rg ->
    // islot = pt*4+q, jslot = jh*4 + rg; po = islot*8 + jslot; k = kt*16+ln.
    float* Ep = (float*)smem;                          // 64 rows x 128 floats
    const float invR = 1.0f / 128.0f;
    #pragma unroll
    for (int s = 0; s < 2; ++s) {
        const int kk = ((w & 3) * 2 + s) * 16 + ln;
        const int u  = kk >> 2, kl = kk & 3;
        #pragma unroll
        for (int pt = 0; pt < 2; ++pt)
            #pragma unroll
            for (int rg = 0; rg < 4; ++rg) {
                const int po = (pt * 4 + q) * 8 + jh * 4 + rg;
                Ep[po * 128 + ((u ^ (po & 7)) << 2) + kl] = cacc[s * 2 + pt][rg] * invR;
            }
    }
    __syncthreads();

    #pragma unroll
    for (int e = 0; e < 4; ++e) {
        const int fid = e * 512 + tid;
        const int po  = fid >> 5, kq = fid & 31;
        const float4 v  = *(const float4*)(Ep + po * 128 + ((kq ^ (po & 7)) << 2));
        const float4 bv = *(const float4*)(b2 + kq * 4);
        float4 o;
        o.x = xv[e].x + v.x + bv.x; o.y = xv[e].y + v.y + bv.y;
        o.z = xv[e].z + v.z + bv.z; o.w = xv[e].w + v.w + bv.w;
        *(float4*)(out + gb[e]) = o;
    }
}

extern "C" void kernel_launch(void* const* d_in, const int* in_sizes, int n_in,
                              void* d_out, int out_size, void* d_ws, size_t ws_size,
                              hipStream_t stream) {
    const float* x  = (const float*)d_in[0];
    const float* m  = (const float*)d_in[1];
    const float* W1 = (const float*)d_in[2];
    const float* b1 = (const float*)d_in[3];
    const float* W2 = (const float*)d_in[4];
    const float* b2 = (const float*)d_in[5];
    float* out = (float*)d_out;

    unsigned short* mpF = (unsigned short*)d_ws;               // 512*2048 h = 2 MB
    unsigned short* W2f = mpF + (size_t)512 * 2048;            // 131072 h = 256 KB

    prep_kernel<<<dim3(576), dim3(256), 0, stream>>>(m, W1, b1, W2, mpF, W2f);
    fused_kernel<<<dim3(32, 32), dim3(512), 0, stream>>>(x, b2, mpF, W2f, out);
}

// Round 5
// 139.978 us; speedup vs baseline: 1.1593x; 1.1593x over previous
//
#include <hip/hip_runtime.h>
#include <stdint.h>

// B=1, R=128, L=256, IN=128, DM=32, DIM=128
// out[i,j,k] = x[i,j,k] + (1/R)*sum_{r,c,d} mp[r,j,c]*mp[r,i,d]*W2[k,c*32+d] + b2[k]
// mp[r,i,d]  = sum_e m[r,i,e]*W1[d,e] + b1[d]
//
// mpF[rt][kr][lane][j]  rt=(i*32+d)>>4 (512), kr=r>>5 (4):
//     value mp[r = kr*32 + (lane>>4)*8 + j][row = rt*16 + (lane&15)]
// W2f[nt][kc][lane][j]  nt=kout>>4 (8), kc=d (32):
//     value W2t[kout=nt*16+(lane&15)][cd' = kc*32 + (lane>>4)*8 + j]
//
// LEDGER: r0=58us fused (THIS structure, reg-staged Bs). r2=62 (B from L2).
// r1/r3/r4 all SPILLED (WRITE_SIZE 84-98MB = scratch): forced launch_bounds,
// merged-d, and j-split-with-naked-global-W2f-loads all blew the register
// budget. Healthy register recipe: acc[2][4]+cacc[4] accumulators + ONE
// explicit wv[8] rolling W2f buffer; do not add unconstrained unrolled
// global loads. Occupancy is pinned at 4 waves/SIMD (2 blocks/CU) in every
// healthy config.
//
// This round vs r0: Bs staging via __builtin_amdgcn_global_load_lds(16B)
// instead of global->VGPR->LDS (frees stg[4]=16 VGPRs, deletes stage VALU).
// Staging layout is linear in tid (chunk cid=r*512+tid -> LDS byte cid*16 =
// wave-uniform base + lane*16), exactly the HW's wave-uniform-dest rule.
// d1 staging issues right after the barrier that retires Bs(d0) readers and
// lands during stepC; the following barrier's vmcnt(0) drain completes it.

typedef __attribute__((ext_vector_type(8))) short bf16x8;
typedef __attribute__((ext_vector_type(4))) float f32x4;

#define MFMA16 __builtin_amdgcn_mfma_f32_16x16x32_bf16

__device__ __forceinline__ unsigned short f2bf(float f) {
    union { float f; unsigned int u; } x; x.f = f;
    unsigned int r = (x.u + 0x7fffu + ((x.u >> 16) & 1u)) >> 16;  // RNE
    return (unsigned short)r;
}

__device__ __forceinline__ bf16x8 load8f_bf(const float* p) {
    float4 v0 = *(const float4*)p;
    float4 v1 = *(const float4*)(p + 4);
    union { bf16x8 v; unsigned short u[8]; } r;
    r.u[0] = f2bf(v0.x); r.u[1] = f2bf(v0.y); r.u[2] = f2bf(v0.z); r.u[3] = f2bf(v0.w);
    r.u[4] = f2bf(v1.x); r.u[5] = f2bf(v1.y); r.u[6] = f2bf(v1.z); r.u[7] = f2bf(v1.w);
    return r.v;
}

// ---------------------------------------------------------------------------
// prep: blocks 0..511 -> mp GEMM -> mpF; blocks 512..575 -> W2 -> W2f
// ---------------------------------------------------------------------------
__global__ __launch_bounds__(256) void prep_kernel(
    const float* __restrict__ m, const float* __restrict__ W1,
    const float* __restrict__ pb1, const float* __restrict__ W2,
    unsigned short* __restrict__ mpF, unsigned short* __restrict__ W2f)
{
    const int bx = blockIdx.x;
    if (bx >= 512) {
        const int t    = (bx - 512) * 256 + threadIdx.x;   // 0..16383
        const int nt   = t >> 11;
        const int kc   = (t >> 6) & 31;
        const int lane = t & 63;
        const int ln   = lane & 15, q = lane >> 4;
        const float* src = W2 + (size_t)(nt * 16 + ln) * 1024 + kc;
        union { bf16x8 v; unsigned short u[8]; } r;
        #pragma unroll
        for (int j = 0; j < 8; ++j)
            r.u[j] = f2bf(src[(q * 8 + j) * 32]);
        *(bf16x8*)(W2f + (size_t)t * 8) = r.v;
        return;
    }
    const int lane = threadIdx.x & 63;
    const int w    = threadIdx.x >> 6;
    const int ln   = lane & 15, q = lane >> 4;
    const int tile = bx * 4 + w;          // 0..2047
    const int i    = tile >> 3;           // 0..255
    const int r0   = (tile & 7) * 16;     // r-tile base

    const float* Ap  = m  + ((size_t)(r0 + ln) * 256 + i) * 128 + q * 8;
    const float* Bp0 = W1 + (size_t)ln * 128 + q * 8;
    const float* Bp1 = W1 + (size_t)(16 + ln) * 128 + q * 8;

    f32x4 acc0 = {0.f, 0.f, 0.f, 0.f};
    f32x4 acc1 = {0.f, 0.f, 0.f, 0.f};
    #pragma unroll
    for (int ke = 0; ke < 4; ++ke) {
        bf16x8 a  = load8f_bf(Ap  + ke * 32);
        bf16x8 b0 = load8f_bf(Bp0 + ke * 32);
        bf16x8 b1 = load8f_bf(Bp1 + ke * 32);
        acc0 = MFMA16(a, b0, acc0, 0, 0, 0);
        acc1 = MFMA16(a, b1, acc1, 0, 0, 0);
    }
    const float bb0 = pb1[ln];
    const float bb1 = pb1[16 + ln];
    const int kr = r0 >> 5;
    const int qr = ((r0 >> 4) & 1) * 2 + (q >> 1);
    const int j0 = (q & 1) * 4;
    const size_t off0 = (size_t)(i * 2 + 0) * 2048 + kr * 512 + (qr * 16 + ln) * 8 + j0;
    const size_t off1 = (size_t)(i * 2 + 1) * 2048 + kr * 512 + (qr * 16 + ln) * 8 + j0;
    ushort4 o0, o1;
    o0.x = f2bf(acc0[0] + bb0); o0.y = f2bf(acc0[1] + bb0);
    o0.z = f2bf(acc0[2] + bb0); o0.w = f2bf(acc0[3] + bb0);
    o1.x = f2bf(acc1[0] + bb1); o1.y = f2bf(acc1[1] + bb1);
    o1.z = f2bf(acc1[2] + bb1); o1.w = f2bf(acc1[3] + bb1);
    *(ushort4*)(mpF + off0) = o0;
    *(ushort4*)(mpF + off1) = o1;
}

// ---------------------------------------------------------------------------
// fused helpers
// ---------------------------------------------------------------------------
// Direct global->LDS staging of one d-half of the block's 8 i-rows into Bs.
// Chunk cid = r*512 + tid is linear in tid, so LDS byte offset cid*16 is
// wave-uniform base + lane*16 (the HW requirement for global_load_lds).
__device__ __forceinline__ void stage_lds(const unsigned short* __restrict__ mpF,
                                          unsigned short* __restrict__ Bs,
                                          int i0, int dhalf, int tid)
{
    #pragma unroll
    for (int r = 0; r < 4; ++r) {
        const int cid = r * 512 + tid;            // 0..2047 (16B chunks)
        const int it  = cid >> 8;                 // i-slot 0..7
        const int pos = cid & 255;                // 16B unit within 4KB row
        const unsigned short* src =
            mpF + (size_t)((i0 + it) * 2 + dhalf) * 2048 + pos * 8;
        __builtin_amdgcn_global_load_lds(
            (const __attribute__((address_space(1))) unsigned int*)src,
            (__attribute__((address_space(3))) unsigned int*)(Bs + (size_t)cid * 8),
            16, 0, 0);
    }
}

__device__ __forceinline__ void stepB(const unsigned short* __restrict__ Ab,
                                      const unsigned short* __restrict__ Bs,
                                      int wn, int lane, f32x4 (&acc)[2][4])
{
    #pragma unroll
    for (int a = 0; a < 2; ++a)
        #pragma unroll
        for (int b = 0; b < 4; ++b)
            acc[a][b] = (f32x4){0.f, 0.f, 0.f, 0.f};
    #pragma unroll
    for (int ks = 0; ks < 4; ++ks) {
        bf16x8 av[2], bv[4];
        av[0] = *(const bf16x8*)(Ab + ks * 512);
        av[1] = *(const bf16x8*)(Ab + 2048 + ks * 512);
        #pragma unroll
        for (int bn = 0; bn < 4; ++bn)
            bv[bn] = *(const bf16x8*)(Bs + (wn * 4 + bn) * 2048 + ks * 512 + lane * 8);
        #pragma unroll
        for (int am = 0; am < 2; ++am)
            #pragma unroll
            for (int bn = 0; bn < 4; ++bn)
                acc[am][bn] = MFMA16(av[am], bv[bn], acc[am][bn], 0, 0, 0);
    }
}

__device__ __forceinline__ void gwrite(unsigned short* __restrict__ Gl,
                                       const f32x4 (&acc)[2][4],
                                       int ln, int q, int wm, int wn)
{
    #pragma unroll
    for (int am = 0; am < 2; ++am) {
        const int chunk = ln * 4 + am * 2 + (q >> 1);
        const int sig   = chunk >> 3;
        const int hbase = chunk * 256 + (q & 1) * 4;
        #pragma unroll
        for (int bn = 0; bn < 4; ++bn) {
            const int p  = (wn * 4 + bn) * 4 + wm;
            const int pp = p ^ sig;
            ushort4 g;
            g.x = f2bf(acc[am][bn][0]); g.y = f2bf(acc[am][bn][1]);
            g.z = f2bf(acc[am][bn][2]); g.w = f2bf(acc[am][bn][3]);
            *(ushort4*)(Gl + hbase + pp * 8) = g;
        }
    }
}

__device__ __forceinline__ void wpre(const unsigned short* __restrict__ wp, bf16x8 (&wv)[8])
{
    #pragma unroll
    for (int k8 = 0; k8 < 8; ++k8)
        wv[k8] = *(const bf16x8*)(wp + k8 * 512);
}

__device__ __forceinline__ void stepC(const unsigned short* __restrict__ Gl,
                                      const unsigned short* __restrict__ wp,
                                      bf16x8 (&wv)[8], int ln, int q,
                                      f32x4& c0, f32x4& c1)
{
    #pragma unroll
    for (int ks = 0; ks < 16; ++ks) {
        bf16x8 cur = wv[ks & 7];
        if (ks < 8) wv[ks & 7] = *(const bf16x8*)(wp + (ks + 8) * 512);
        const int chunk = ks * 4 + q;
        const int sig   = chunk >> 3;
        const unsigned short* gp = Gl + chunk * 256 + ((ln ^ sig) << 3);
        bf16x8 ag0 = *(const bf16x8*)gp;          // pairs 0..15
        bf16x8 ag1 = *(const bf16x8*)(gp + 128);  // pairs 16..31
        c0 = MFMA16(ag0, cur, c0, 0, 0, 0);
        c1 = MFMA16(ag1, cur, c1, 0, 0, 0);
    }
}

// ---------------------------------------------------------------------------
// fused: block = 8i x 8j (64 pairs), 2 d-halves x 2 j-halves.
// ---------------------------------------------------------------------------
__global__ __launch_bounds__(512, 4) void fused_kernel(
    const float* __restrict__ x, const float* __restrict__ b2,
    const unsigned short* __restrict__ mpF, const unsigned short* __restrict__ W2f,
    float* __restrict__ out)
{
    __shared__ __align__(16) unsigned char smem[65536];
    unsigned short* Gl = (unsigned short*)smem;            // 64 chunks x 256 shorts
    unsigned short* Bs = (unsigned short*)(smem + 32768);  // 8 i x 2048 shorts

    const int tid  = threadIdx.x;
    const int lane = tid & 63, w = tid >> 6;
    const int ln   = lane & 15, q = lane >> 4;
    const int wm   = w & 3, wn = w >> 2;

    const int i0 = blockIdx.x * 8;            // gridDim.x = 32
    const int j0 = blockIdx.y * 8;            // gridDim.y = 32

    const unsigned short* Ab0 = mpF + (size_t)((j0 + wm) * 2) * 2048 + lane * 8;
    const unsigned short* Ab1 = Ab0 + 16384;                   // +4 j rows
    const unsigned short* wp0 = W2f + (size_t)(w * 32) * 512 + lane * 8;
    const unsigned short* wp1 = wp0 + 16 * 512;

    f32x4 cacc[4];
    #pragma unroll
    for (int t = 0; t < 4; ++t) cacc[t] = (f32x4){0.f, 0.f, 0.f, 0.f};
    f32x4 acc[2][4];
    bf16x8 wv[8];

    // ---- stage Bs(d0): direct global->LDS, drained by the barrier ----
    stage_lds(mpF, Bs, i0, 0, tid);
    __syncthreads();                                   // Bs(d0) ready

    // ---- (j0, d0) ----
    stepB(Ab0, Bs, wn, lane, acc);
    wpre(wp0, wv);
    gwrite(Gl, acc, ln, q, wm, wn);
    __syncthreads();                                   // Gl(j0,d0) ready
    stepC(Gl, wp0, wv, ln, q, cacc[0], cacc[1]);

    // ---- (j1, d0): stepB early (regs only) ----
    stepB(Ab1, Bs, wn, lane, acc);
    __syncthreads();                                   // Gl(j0,d0) reads done
    wpre(wp0, wv);
    gwrite(Gl, acc, ln, q, wm, wn);
    __syncthreads();                                   // Gl(j1,d0) ready; Bs(d0) dead
    stage_lds(mpF, Bs, i0, 1, tid);                    // d1 staging lands during stepC
    stepC(Gl, wp0, wv, ln, q, cacc[2], cacc[3]);
    __syncthreads();                                   // Bs(d1) ready + Gl reads done

    // ---- (j0, d1) ----
    stepB(Ab0, Bs, wn, lane, acc);
    wpre(wp1, wv);
    gwrite(Gl, acc, ln, q, wm, wn);
    __syncthreads();                                   // Gl(j0,d1) ready
    stepC(Gl, wp1, wv, ln, q, cacc[0], cacc[1]);

    // ---- (j1, d1) ----
    stepB(Ab1, Bs, wn, lane, acc);
    __syncthreads();                                   // Gl(j0,d1) reads done
    wpre(wp1, wv);
    gwrite(Gl, acc, ln, q, wm, wn);
    __syncthreads();                                   // Gl(j1,d1) ready

    // prefetch x while stepC runs
    float4 xv[4];
    size_t gb[4];
    #pragma unroll
    for (int e = 0; e < 4; ++e) {
        const int fid = e * 512 + tid;                 // 0..2047 float4 units
        const int po  = fid >> 5, kq = fid & 31;
        gb[e] = ((size_t)(i0 + (po >> 3)) * 256 + (j0 + (po & 7))) * 128 + kq * 4;
        xv[e] = *(const float4*)(x + gb[e]);
    }

    stepC(Gl, wp1, wv, ln, q, cacc[2], cacc[3]);
    __syncthreads();                                   // all Gl reads done -> Ep

    // ---- epilogue: LDS transpose (XOR-swizzled cols), coalesced out ----
    float* Ep = (float*)smem;                          // 64 rows x 128 floats
    const float invR = 1.0f / 128.0f;
    const int kk = w * 16 + ln;
    const int u  = kk >> 2, kl = kk & 3;
    #pragma unroll
    for (int jh = 0; jh < 2; ++jh)
        #pragma unroll
        for (int pt = 0; pt < 2; ++pt)
            #pragma unroll
            for (int rg = 0; rg < 4; ++rg) {
                const int po = (pt * 4 + q) * 8 + jh * 4 + rg;
                Ep[po * 128 + ((u ^ (po & 7)) << 2) + kl] = cacc[jh * 2 + pt][rg] * invR;
            }
    __syncthreads();

    #pragma unroll
    for (int e = 0; e < 4; ++e) {
        const int fid = e * 512 + tid;
        const int po  = fid >> 5, kq = fid & 31;
        const float4 v  = *(const float4*)(Ep + po * 128 + ((kq ^ (po & 7)) << 2));
        const float4 bv = *(const float4*)(b2 + kq * 4);
        float4 o;
        o.x = xv[e].x + v.x + bv.x; o.y = xv[e].y + v.y + bv.y;
        o.z = xv[e].z + v.z + bv.z; o.w = xv[e].w + v.w + bv.w;
        *(float4*)(out + gb[e]) = o;
    }
}

extern "C" void kernel_launch(void* const* d_in, const int* in_sizes, int n_in,
                              void* d_out, int out_size, void* d_ws, size_t ws_size,
                              hipStream_t stream) {
    const float* x  = (const float*)d_in[0];
    const float* m  = (const float*)d_in[1];
    const float* W1 = (const float*)d_in[2];
    const float* b1 = (const float*)d_in[3];
    const float* W2 = (const float*)d_in[4];
    const float* b2 = (const float*)d_in[5];
    float* out = (float*)d_out;

    unsigned short* mpF = (unsigned short*)d_ws;               // 512*2048 h = 2 MB
    unsigned short* W2f = mpF + (size_t)512 * 2048;            // 131072 h = 256 KB

    prep_kernel<<<dim3(576), dim3(256), 0, stream>>>(m, W1, b1, W2, mpF, W2f);
    fused_kernel<<<dim3(32, 32), dim3(512), 0, stream>>>(x, b2, mpF, W2f, out);
}

// Round 6
// 138.241 us; speedup vs baseline: 1.1738x; 1.0126x over previous
//
#include <hip/hip_runtime.h>
#include <stdint.h>

// B=1, R=128, L=256, IN=128, DM=32, DIM=128
// out[i,j,k] = x[i,j,k] + (1/R)*sum_{r,c,d} mp[r,j,c]*mp[r,i,d]*W2[k,c*32+d] + b2[k]
// mp[r,i,d]  = sum_e m[r,i,e]*W1[d,e] + b1[d]
//
// mpF[rt][kr][lane][j]  rt=(i*32+d)>>4 (512), kr=r>>5 (4):
//     value mp[r = kr*32 + (lane>>4)*8 + j][row = rt*16 + (lane&15)]
// W2f[nt][kc][lane][j]  nt=kout>>4 (8), kc=d (32):
//     value W2t[kout=nt*16+(lane&15)][cd' = kc*32 + (lane>>4)*8 + j]
//
// LEDGER: r0=58us fused (reg-staged Bs). r2=62 (B from L2). r1/r3/r4 SPILLED.
// r5=53us (global_load_lds staging, no spill). REGISTER BUDGET RESOLVED:
// VGPR_Count=64 arch + ~64 AGPR accumulators = 128 total = EXACTLY the
// 4-waves/SIMD cap on the unified gfx950 file. Zero headroom: any added live
// state spills (r1/r3/r4 evidence). Design space = this register footprint,
// <=80 KiB LDS, 2 blocks/CU.
//
// This round: + s_setprio(1/0) around MFMA clusters (T5). Phase diversity
// comes from the OTHER resident block (independent point in its barrier
// chain) - the m191-attn precondition, not the m190-lockstep null case.

typedef __attribute__((ext_vector_type(8))) short bf16x8;
typedef __attribute__((ext_vector_type(4))) float f32x4;

#define MFMA16 __builtin_amdgcn_mfma_f32_16x16x32_bf16

__device__ __forceinline__ unsigned short f2bf(float f) {
    union { float f; unsigned int u; } x; x.f = f;
    unsigned int r = (x.u + 0x7fffu + ((x.u >> 16) & 1u)) >> 16;  // RNE
    return (unsigned short)r;
}

__device__ __forceinline__ bf16x8 load8f_bf(const float* p) {
    float4 v0 = *(const float4*)p;
    float4 v1 = *(const float4*)(p + 4);
    union { bf16x8 v; unsigned short u[8]; } r;
    r.u[0] = f2bf(v0.x); r.u[1] = f2bf(v0.y); r.u[2] = f2bf(v0.z); r.u[3] = f2bf(v0.w);
    r.u[4] = f2bf(v1.x); r.u[5] = f2bf(v1.y); r.u[6] = f2bf(v1.z); r.u[7] = f2bf(v1.w);
    return r.v;
}

// ---------------------------------------------------------------------------
// prep: blocks 0..511 -> mp GEMM -> mpF; blocks 512..575 -> W2 -> W2f
// ---------------------------------------------------------------------------
__global__ __launch_bounds__(256) void prep_kernel(
    const float* __restrict__ m, const float* __restrict__ W1,
    const float* __restrict__ pb1, const float* __restrict__ W2,
    unsigned short* __restrict__ mpF, unsigned short* __restrict__ W2f)
{
    const int bx = blockIdx.x;
    if (bx >= 512) {
        const int t    = (bx - 512) * 256 + threadIdx.x;   // 0..16383
        const int nt   = t >> 11;
        const int kc   = (t >> 6) & 31;
        const int lane = t & 63;
        const int ln   = lane & 15, q = lane >> 4;
        const float* src = W2 + (size_t)(nt * 16 + ln) * 1024 + kc;
        union { bf16x8 v; unsigned short u[8]; } r;
        #pragma unroll
        for (int j = 0; j < 8; ++j)
            r.u[j] = f2bf(src[(q * 8 + j) * 32]);
        *(bf16x8*)(W2f + (size_t)t * 8) = r.v;
        return;
    }
    const int lane = threadIdx.x & 63;
    const int w    = threadIdx.x >> 6;
    const int ln   = lane & 15, q = lane >> 4;
    const int tile = bx * 4 + w;          // 0..2047
    const int i    = tile >> 3;           // 0..255
    const int r0   = (tile & 7) * 16;     // r-tile base

    const float* Ap  = m  + ((size_t)(r0 + ln) * 256 + i) * 128 + q * 8;
    const float* Bp0 = W1 + (size_t)ln * 128 + q * 8;
    const float* Bp1 = W1 + (size_t)(16 + ln) * 128 + q * 8;

    f32x4 acc0 = {0.f, 0.f, 0.f, 0.f};
    f32x4 acc1 = {0.f, 0.f, 0.f, 0.f};
    #pragma unroll
    for (int ke = 0; ke < 4; ++ke) {
        bf16x8 a  = load8f_bf(Ap  + ke * 32);
        bf16x8 b0 = load8f_bf(Bp0 + ke * 32);
        bf16x8 b1 = load8f_bf(Bp1 + ke * 32);
        acc0 = MFMA16(a, b0, acc0, 0, 0, 0);
        acc1 = MFMA16(a, b1, acc1, 0, 0, 0);
    }
    const float bb0 = pb1[ln];
    const float bb1 = pb1[16 + ln];
    const int kr = r0 >> 5;
    const int qr = ((r0 >> 4) & 1) * 2 + (q >> 1);
    const int j0 = (q & 1) * 4;
    const size_t off0 = (size_t)(i * 2 + 0) * 2048 + kr * 512 + (qr * 16 + ln) * 8 + j0;
    const size_t off1 = (size_t)(i * 2 + 1) * 2048 + kr * 512 + (qr * 16 + ln) * 8 + j0;
    ushort4 o0, o1;
    o0.x = f2bf(acc0[0] + bb0); o0.y = f2bf(acc0[1] + bb0);
    o0.z = f2bf(acc0[2] + bb0); o0.w = f2bf(acc0[3] + bb0);
    o1.x = f2bf(acc1[0] + bb1); o1.y = f2bf(acc1[1] + bb1);
    o1.z = f2bf(acc1[2] + bb1); o1.w = f2bf(acc1[3] + bb1);
    *(ushort4*)(mpF + off0) = o0;
    *(ushort4*)(mpF + off1) = o1;
}

// ---------------------------------------------------------------------------
// fused helpers
// ---------------------------------------------------------------------------
// Direct global->LDS staging of one d-half of the block's 8 i-rows into Bs.
// Chunk cid = r*512 + tid is linear in tid, so LDS byte offset cid*16 is
// wave-uniform base + lane*16 (the HW requirement for global_load_lds).
__device__ __forceinline__ void stage_lds(const unsigned short* __restrict__ mpF,
                                          unsigned short* __restrict__ Bs,
                                          int i0, int dhalf, int tid)
{
    #pragma unroll
    for (int r = 0; r < 4; ++r) {
        const int cid = r * 512 + tid;            // 0..2047 (16B chunks)
        const int it  = cid >> 8;                 // i-slot 0..7
        const int pos = cid & 255;                // 16B unit within 4KB row
        const unsigned short* src =
            mpF + (size_t)((i0 + it) * 2 + dhalf) * 2048 + pos * 8;
        __builtin_amdgcn_global_load_lds(
            (const __attribute__((address_space(1))) unsigned int*)src,
            (__attribute__((address_space(3))) unsigned int*)(Bs + (size_t)cid * 8),
            16, 0, 0);
    }
}

__device__ __forceinline__ void stepB(const unsigned short* __restrict__ Ab,
                                      const unsigned short* __restrict__ Bs,
                                      int wn, int lane, f32x4 (&acc)[2][4])
{
    #pragma unroll
    for (int a = 0; a < 2; ++a)
        #pragma unroll
        for (int b = 0; b < 4; ++b)
            acc[a][b] = (f32x4){0.f, 0.f, 0.f, 0.f};
    #pragma unroll
    for (int ks = 0; ks < 4; ++ks) {
        bf16x8 av[2], bv[4];
        av[0] = *(const bf16x8*)(Ab + ks * 512);
        av[1] = *(const bf16x8*)(Ab + 2048 + ks * 512);
        #pragma unroll
        for (int bn = 0; bn < 4; ++bn)
            bv[bn] = *(const bf16x8*)(Bs + (wn * 4 + bn) * 2048 + ks * 512 + lane * 8);
        __builtin_amdgcn_s_setprio(1);
        #pragma unroll
        for (int am = 0; am < 2; ++am)
            #pragma unroll
            for (int bn = 0; bn < 4; ++bn)
                acc[am][bn] = MFMA16(av[am], bv[bn], acc[am][bn], 0, 0, 0);
        __builtin_amdgcn_s_setprio(0);
    }
}

__device__ __forceinline__ void gwrite(unsigned short* __restrict__ Gl,
                                       const f32x4 (&acc)[2][4],
                                       int ln, int q, int wm, int wn)
{
    #pragma unroll
    for (int am = 0; am < 2; ++am) {
        const int chunk = ln * 4 + am * 2 + (q >> 1);
        const int sig   = chunk >> 3;
        const int hbase = chunk * 256 + (q & 1) * 4;
        #pragma unroll
        for (int bn = 0; bn < 4; ++bn) {
            const int p  = (wn * 4 + bn) * 4 + wm;
            const int pp = p ^ sig;
            ushort4 g;
            g.x = f2bf(acc[am][bn][0]); g.y = f2bf(acc[am][bn][1]);
            g.z = f2bf(acc[am][bn][2]); g.w = f2bf(acc[am][bn][3]);
            *(ushort4*)(Gl + hbase + pp * 8) = g;
        }
    }
}

__device__ __forceinline__ void wpre(const unsigned short* __restrict__ wp, bf16x8 (&wv)[8])
{
    #pragma unroll
    for (int k8 = 0; k8 < 8; ++k8)
        wv[k8] = *(const bf16x8*)(wp + k8 * 512);
}

__device__ __forceinline__ void stepC(const unsigned short* __restrict__ Gl,
                                      const unsigned short* __restrict__ wp,
                                      bf16x8 (&wv)[8], int ln, int q,
                                      f32x4& c0, f32x4& c1)
{
    #pragma unroll
    for (int ks = 0; ks < 16; ++ks) {
        bf16x8 cur = wv[ks & 7];
        if (ks < 8) wv[ks & 7] = *(const bf16x8*)(wp + (ks + 8) * 512);
        const int chunk = ks * 4 + q;
        const int sig   = chunk >> 3;
        const unsigned short* gp = Gl + chunk * 256 + ((ln ^ sig) << 3);
        bf16x8 ag0 = *(const bf16x8*)gp;          // pairs 0..15
        bf16x8 ag1 = *(const bf16x8*)(gp + 128);  // pairs 16..31
        __builtin_amdgcn_s_setprio(1);
        c0 = MFMA16(ag0, cur, c0, 0, 0, 0);
        c1 = MFMA16(ag1, cur, c1, 0, 0, 0);
        __builtin_amdgcn_s_setprio(0);
    }
}

// ---------------------------------------------------------------------------
// fused: block = 8i x 8j (64 pairs), 2 d-halves x 2 j-halves.
// ---------------------------------------------------------------------------
__global__ __launch_bounds__(512, 4) void fused_kernel(
    const float* __restrict__ x, const float* __restrict__ b2,
    const unsigned short* __restrict__ mpF, const unsigned short* __restrict__ W2f,
    float* __restrict__ out)
{
    __shared__ __align__(16) unsigned char smem[65536];
    unsigned short* Gl = (unsigned short*)smem;            // 64 chunks x 256 shorts
    unsigned short* Bs = (unsigned short*)(smem + 32768);  // 8 i x 2048 shorts

    const int tid  = threadIdx.x;
    const int lane = tid & 63, w = tid >> 6;
    const int ln   = lane & 15, q = lane >> 4;
    const int wm   = w & 3, wn = w >> 2;

    const int i0 = blockIdx.x * 8;            // gridDim.x = 32
    const int j0 = blockIdx.y * 8;            // gridDim.y = 32

    const unsigned short* Ab0 = mpF + (size_t)((j0 + wm) * 2) * 2048 + lane * 8;
    const unsigned short* Ab1 = Ab0 + 16384;                   // +4 j rows
    const unsigned short* wp0 = W2f + (size_t)(w * 32) * 512 + lane * 8;
    const unsigned short* wp1 = wp0 + 16 * 512;

    f32x4 cacc[4];
    #pragma unroll
    for (int t = 0; t < 4; ++t) cacc[t] = (f32x4){0.f, 0.f, 0.f, 0.f};
    f32x4 acc[2][4];
    bf16x8 wv[8];

    // ---- stage Bs(d0): direct global->LDS, drained by the barrier ----
    stage_lds(mpF, Bs, i0, 0, tid);
    __syncthreads();                                   // Bs(d0) ready

    // ---- (j0, d0) ----
    stepB(Ab0, Bs, wn, lane, acc);
    wpre(wp0, wv);
    gwrite(Gl, acc, ln, q, wm, wn);
    __syncthreads();                                   // Gl(j0,d0) ready
    stepC(Gl, wp0, wv, ln, q, cacc[0], cacc[1]);

    // ---- (j1, d0): stepB early (regs only) ----
    stepB(Ab1, Bs, wn, lane, acc);
    __syncthreads();                                   // Gl(j0,d0) reads done
    wpre(wp0, wv);
    gwrite(Gl, acc, ln, q, wm, wn);
    __syncthreads();                                   // Gl(j1,d0) ready; Bs(d0) dead
    stage_lds(mpF, Bs, i0, 1, tid);                    // d1 staging lands during stepC
    stepC(Gl, wp0, wv, ln, q, cacc[2], cacc[3]);
    __syncthreads();                                   // Bs(d1) ready + Gl reads done

    // ---- (j0, d1) ----
    stepB(Ab0, Bs, wn, lane, acc);
    wpre(wp1, wv);
    gwrite(Gl, acc, ln, q, wm, wn);
    __syncthreads();                                   // Gl(j0,d1) ready
    stepC(Gl, wp1, wv, ln, q, cacc[0], cacc[1]);

    // ---- (j1, d1) ----
    stepB(Ab1, Bs, wn, lane, acc);
    __syncthreads();                                   // Gl(j0,d1) reads done
    wpre(wp1, wv);
    gwrite(Gl, acc, ln, q, wm, wn);
    __syncthreads();                                   // Gl(j1,d1) ready

    // prefetch x while stepC runs
    float4 xv[4];
    size_t gb[4];
    #pragma unroll
    for (int e = 0; e < 4; ++e) {
        const int fid = e * 512 + tid;                 // 0..2047 float4 units
        const int po  = fid >> 5, kq = fid & 31;
        gb[e] = ((size_t)(i0 + (po >> 3)) * 256 + (j0 + (po & 7))) * 128 + kq * 4;
        xv[e] = *(const float4*)(x + gb[e]);
    }

    stepC(Gl, wp1, wv, ln, q, cacc[2], cacc[3]);
    __syncthreads();                                   // all Gl reads done -> Ep

    // ---- epilogue: LDS transpose (XOR-swizzled cols), coalesced out ----
    float* Ep = (float*)smem;                          // 64 rows x 128 floats
    const float invR = 1.0f / 128.0f;
    const int kk = w * 16 + ln;
    const int u  = kk >> 2, kl = kk & 3;
    #pragma unroll
    for (int jh = 0; jh < 2; ++jh)
        #pragma unroll
        for (int pt = 0; pt < 2; ++pt)
            #pragma unroll
            for (int rg = 0; rg < 4; ++rg) {
                const int po = (pt * 4 + q) * 8 + jh * 4 + rg;
                Ep[po * 128 + ((u ^ (po & 7)) << 2) + kl] = cacc[jh * 2 + pt][rg] * invR;
            }
    __syncthreads();

    #pragma unroll
    for (int e = 0; e < 4; ++e) {
        const int fid = e * 512 + tid;
        const int po  = fid >> 5, kq = fid & 31;
        const float4 v  = *(const float4*)(Ep + po * 128 + ((kq ^ (po & 7)) << 2));
        const float4 bv = *(const float4*)(b2 + kq * 4);
        float4 o;
        o.x = xv[e].x + v.x + bv.x; o.y = xv[e].y + v.y + bv.y;
        o.z = xv[e].z + v.z + bv.z; o.w = xv[e].w + v.w + bv.w;
        *(float4*)(out + gb[e]) = o;
    }
}

extern "C" void kernel_launch(void* const* d_in, const int* in_sizes, int n_in,
                              void* d_out, int out_size, void* d_ws, size_t ws_size,
                              hipStream_t stream) {
    const float* x  = (const float*)d_in[0];
    const float* m  = (const float*)d_in[1];
    const float* W1 = (const float*)d_in[2];
    const float* b1 = (const float*)d_in[3];
    const float* W2 = (const float*)d_in[4];
    const float* b2 = (const float*)d_in[5];
    float* out = (float*)d_out;

    unsigned short* mpF = (unsigned short*)d_ws;               // 512*2048 h = 2 MB
    unsigned short* W2f = mpF + (size_t)512 * 2048;            // 131072 h = 256 KB

    prep_kernel<<<dim3(576), dim3(256), 0, stream>>>(m, W1, b1, W2, mpF, W2f);
    fused_kernel<<<dim3(32, 32), dim3(512), 0, stream>>>(x, b2, mpF, W2f, out);
}